// Round 4
// baseline (6590.247 us; speedup 1.0000x reference)
//
#include <hip/hip_runtime.h>
#include <math.h>

#define U_N 100000
#define I_N 50000
#define DD  64
#define BB  8192
#define TT  30
#define N_EUI 1600000
#define N_EII 800000
#define LN_EPS_ 1e-5f
#define BEH_SCALE_ 0.35f
#define REG_COEF_ 1e-4f

typedef unsigned short us_t;

__device__ __forceinline__ float wave_sum64(float v) {
#pragma unroll
  for (int o = 32; o > 0; o >>= 1) v += __shfl_xor(v, o, 64);
  return v;
}

__device__ __forceinline__ float rdlane(float v, int k) {
  return __int_as_float(__builtin_amdgcn_readlane(__float_as_int(v), k));
}

__device__ __forceinline__ us_t f2bf(float f) {
  unsigned u = __float_as_uint(f);
  u += 0x7fffu + ((u >> 16) & 1u);
  return (us_t)(u >> 16);
}
__device__ __forceinline__ float bf2f(us_t h) {
  return __uint_as_float((unsigned)h << 16);
}

// ---------------- f32 -> bf16 table conversion ----------------
__global__ __launch_bounds__(256) void to_bf16(const float* __restrict__ in,
                                               us_t* __restrict__ out,
                                               long n4) {
  for (long i = (long)blockIdx.x * blockDim.x + threadIdx.x; i < n4;
       i += (long)gridDim.x * blockDim.x) {
    float4 f = ((const float4*)in)[i];
    ushort4 o;
    o.x = f2bf(f.x); o.y = f2bf(f.y); o.z = f2bf(f.z); o.w = f2bf(f.w);
    ((ushort4*)out)[i] = o;
  }
}

// ---------------- CSR build ----------------

__global__ __launch_bounds__(256) void hist_kernel(
    const int* __restrict__ rows, int nE, int* __restrict__ cnt) {
  for (long e = (long)blockIdx.x * blockDim.x + threadIdx.x; e < nE;
       e += (long)gridDim.x * blockDim.x)
    atomicAdd(&cnt[rows[e]], 1);
}

__global__ __launch_bounds__(1024) void ex_scan(
    const int* __restrict__ cnt, int n, int* __restrict__ offs,
    int* __restrict__ cursor) {
  __shared__ int part[1024];
  const int tid = threadIdx.x;
  const int chunk = (n + 1023) / 1024;
  const int lo = tid * chunk;
  const int hi = min(lo + chunk, n);
  int s = 0;
  for (int i = lo; i < hi; ++i) s += cnt[i];
  part[tid] = s;
  __syncthreads();
  for (int off = 1; off < 1024; off <<= 1) {
    int v = part[tid];
    int add = (tid >= off) ? part[tid - off] : 0;
    __syncthreads();
    part[tid] = v + add;
    __syncthreads();
  }
  int base = (tid == 0) ? 0 : part[tid - 1];
  for (int i = lo; i < hi; ++i) {
    int c = cnt[i];  // read BEFORE writing (cnt aliases cursor)
    offs[i] = base;
    cursor[i] = base;
    base += c;
  }
  if (tid == 0) offs[n] = part[1023];
}

__global__ __launch_bounds__(256) void csr_fill(
    const int* __restrict__ drows, const int* __restrict__ srows,
    const float* __restrict__ vals, int nE, int* __restrict__ cursor,
    int2* __restrict__ pairs) {
  for (long e = (long)blockIdx.x * blockDim.x + threadIdx.x; e < nE;
       e += (long)gridDim.x * blockDim.x) {
    int d = drows[e];
    int pos = atomicAdd(&cursor[d], 1);
    pairs[pos] = make_int2(srows[e], __float_as_int(vals[e]));
  }
}

// ---------------- fused GNN layers (bf16 gather, f32 compute) ----------------

__global__ __launch_bounds__(256) void gnn_user_layer(
    const float* __restrict__ cur_u, const us_t* __restrict__ src_bf,
    const int* __restrict__ offs, const int2* __restrict__ pairs,
    const float* __restrict__ W, const float* __restrict__ bias,
    float* __restrict__ out, us_t* __restrict__ out_bf) {
  __shared__ float Wl[DD * DD];
  for (int i = threadIdx.x; i < DD * DD; i += blockDim.x) Wl[i] = W[i];
  __syncthreads();
  const int lane = threadIdx.x & 63;
  const float bn = bias[lane];
  long wid = ((long)blockIdx.x * blockDim.x + threadIdx.x) >> 6;
  long nw = ((long)gridDim.x * blockDim.x) >> 6;
  for (long r = wid; r < U_N; r += nw) {
    float acc = cur_u[r * DD + lane], acc2 = 0.f;
    int j = offs[r], j1 = offs[r + 1];
    for (; j + 1 < j1; j += 2) {
      int2 p0 = pairs[j], p1 = pairs[j + 1];
      acc = fmaf(__int_as_float(p0.y), bf2f(src_bf[(long)p0.x * DD + lane]), acc);
      acc2 = fmaf(__int_as_float(p1.y), bf2f(src_bf[(long)p1.x * DD + lane]), acc2);
    }
    if (j < j1) {
      int2 p = pairs[j];
      acc = fmaf(__int_as_float(p.y), bf2f(src_bf[(long)p.x * DD + lane]), acc);
    }
    acc += acc2;
    float y = bn;
#pragma unroll
    for (int k = 0; k < DD; ++k)
      y = fmaf(rdlane(acc, k), Wl[k * DD + lane], y);
    y = fmaxf(y, 0.f);
    out[r * DD + lane] = y;
    if (out_bf) out_bf[r * DD + lane] = f2bf(y);
  }
}

__global__ __launch_bounds__(256) void gnn_item_layer(
    const float* __restrict__ cur_it, const us_t* __restrict__ it_bf,
    const us_t* __restrict__ u_bf, const int* __restrict__ offsA,
    const int2* __restrict__ pairsA, const int* __restrict__ offsB,
    const int2* __restrict__ pairsB, const float* __restrict__ W,
    const float* __restrict__ bias, float* __restrict__ out,
    us_t* __restrict__ out_bf) {
  __shared__ float Wl[DD * DD];
  for (int i = threadIdx.x; i < DD * DD; i += blockDim.x) Wl[i] = W[i];
  __syncthreads();
  const int lane = threadIdx.x & 63;
  const float bn = bias[lane];
  long wid = ((long)blockIdx.x * blockDim.x + threadIdx.x) >> 6;
  long nw = ((long)gridDim.x * blockDim.x) >> 6;
  for (long r = wid; r < I_N; r += nw) {
    float acc = cur_it[r * DD + lane], acc2 = 0.f;
    int j = offsA[r], j1 = offsA[r + 1];
    for (; j + 1 < j1; j += 2) {
      int2 p0 = pairsA[j], p1 = pairsA[j + 1];
      acc = fmaf(__int_as_float(p0.y), bf2f(it_bf[(long)p0.x * DD + lane]), acc);
      acc2 = fmaf(__int_as_float(p1.y), bf2f(it_bf[(long)p1.x * DD + lane]), acc2);
    }
    if (j < j1) {
      int2 p = pairsA[j];
      acc = fmaf(__int_as_float(p.y), bf2f(it_bf[(long)p.x * DD + lane]), acc);
    }
    j = offsB[r];
    j1 = offsB[r + 1];
    for (; j + 1 < j1; j += 2) {
      int2 p0 = pairsB[j], p1 = pairsB[j + 1];
      acc = fmaf(__int_as_float(p0.y), bf2f(u_bf[(long)p0.x * DD + lane]), acc);
      acc2 = fmaf(__int_as_float(p1.y), bf2f(u_bf[(long)p1.x * DD + lane]), acc2);
    }
    if (j < j1) {
      int2 p = pairsB[j];
      acc = fmaf(__int_as_float(p.y), bf2f(u_bf[(long)p.x * DD + lane]), acc);
    }
    acc += acc2;
    float y = bn;
#pragma unroll
    for (int k = 0; k < DD; ++k)
      y = fmaf(rdlane(acc, k), Wl[k * DD + lane], y);
    y = fmaxf(y, 0.f);
    out[r * DD + lane] = y;
    if (out_bf) out_bf[r * DD + lane] = f2bf(y);
  }
}

// layer-1 user output, only for the 8192 selected users
__global__ __launch_bounds__(256) void gnn_user_sel(
    const float* __restrict__ u_a, const us_t* __restrict__ ita_bf,
    const int* __restrict__ user_idx, const int* __restrict__ offs,
    const int2* __restrict__ pairs, const float* __restrict__ W,
    const float* __restrict__ bias, float* __restrict__ out) {
  __shared__ float Wl[DD * DD];
  for (int i = threadIdx.x; i < DD * DD; i += blockDim.x) Wl[i] = W[i];
  __syncthreads();
  const int lane = threadIdx.x & 63;
  const float bn = bias[lane];
  long wid = ((long)blockIdx.x * blockDim.x + threadIdx.x) >> 6;
  long nw = ((long)gridDim.x * blockDim.x) >> 6;
  for (long b = wid; b < BB; b += nw) {
    int r = user_idx[b];
    float acc = u_a[(long)r * DD + lane], acc2 = 0.f;
    int j = offs[r], j1 = offs[r + 1];
    for (; j + 1 < j1; j += 2) {
      int2 p0 = pairs[j], p1 = pairs[j + 1];
      acc = fmaf(__int_as_float(p0.y), bf2f(ita_bf[(long)p0.x * DD + lane]), acc);
      acc2 = fmaf(__int_as_float(p1.y), bf2f(ita_bf[(long)p1.x * DD + lane]), acc2);
    }
    if (j < j1) {
      int2 p = pairs[j];
      acc = fmaf(__int_as_float(p.y), bf2f(ita_bf[(long)p.x * DD + lane]), acc);
    }
    acc += acc2;
    float y = bn;
#pragma unroll
    for (int k = 0; k < DD; ++k)
      y = fmaf(rdlane(acc, k), Wl[k * DD + lane], y);
    out[b * DD + lane] = fmaxf(y, 0.f);
  }
}

// ---------------- sequence encode + gi = x @ W_ih + b_ih (bf16 out) --------

__global__ __launch_bounds__(256) void seq_encode_gi(
    const float* __restrict__ itf, const float* __restrict__ beh_emb,
    const float* __restrict__ t_w1, const float* __restrict__ t_b1,
    const float* __restrict__ t_w2, const float* __restrict__ t_b2,
    const float* __restrict__ ln_g, const float* __restrict__ ln_b,
    const float* __restrict__ Wih, const float* __restrict__ bih,
    const float* __restrict__ delta, const int* __restrict__ items,
    const int* __restrict__ behs, us_t* __restrict__ gi) {
  __shared__ float W2[DD * DD];    // 16 KB
  __shared__ float WI[DD * 192];   // 48 KB
  for (int i = threadIdx.x; i < DD * DD; i += blockDim.x) W2[i] = t_w2[i];
  for (int i = threadIdx.x; i < DD * 192; i += blockDim.x) WI[i] = Wih[i];
  __syncthreads();
  const int lane = threadIdx.x & 63;
  const float w1 = t_w1[lane], b1 = t_b1[lane], b2 = t_b2[lane];
  const float g = ln_g[lane], bo = ln_b[lane];
  const float bi0 = bih[lane], bi1 = bih[64 + lane], bi2 = bih[128 + lane];
  long wid = ((long)blockIdx.x * blockDim.x + threadIdx.x) >> 6;
  long nw = ((long)gridDim.x * blockDim.x) >> 6;
  const long NR = (long)BB * TT;
  for (long r = wid; r < NR; r += nw) {
    int it = items[r];
    int bh = behs[r];
    float x = itf[(long)it * DD + lane] + BEH_SCALE_ * beh_emb[bh * DD + lane];
    float tv = log1pf(delta[r]);
    float tmp = fmaxf(fmaf(tv, w1, b1), 0.f);
    float y = b2;
#pragma unroll
    for (int k = 0; k < DD; ++k)
      y = fmaf(rdlane(tmp, k), W2[k * DD + lane], y);
    x += y;
    float mu = wave_sum64(x) * (1.f / DD);
    float xc = x - mu;
    float var = wave_sum64(xc * xc) * (1.f / DD);
    float xo = xc * rsqrtf(var + LN_EPS_) * g + bo;
    // gi = xo @ Wih + bih  (lane covers cols lane, lane+64, lane+128)
    float g0 = bi0, g1 = bi1, g2 = bi2;
#pragma unroll
    for (int k = 0; k < DD; ++k) {
      float xv = rdlane(xo, k);
      g0 = fmaf(xv, WI[k * 192 + lane], g0);
      g1 = fmaf(xv, WI[k * 192 + 64 + lane], g1);
      g2 = fmaf(xv, WI[k * 192 + 128 + lane], g2);
    }
    us_t* go = gi + r * 192;
    go[lane] = f2bf(g0);
    go[64 + lane] = f2bf(g1);
    go[128 + lane] = f2bf(g2);
  }
}

// ---------------- GRU scan: only h@W_hh in the loop ----------------
// Block = 16 rows, 256 threads: thread (rt=tid>>4, ct=tid&15) owns row rt,
// dims d0..d0+3 of all 3 gates. W_hh f32 in LDS (48KB) + hT (4.6KB) -> 2 blk/CU.
#define HSTR 18
__global__ __launch_bounds__(256) void gru_scan3(
    const us_t* __restrict__ gi, const float* __restrict__ Whh,
    const float* __restrict__ bhh, const int* __restrict__ seq_len,
    float* __restrict__ hfin) {
  __shared__ float sW[DD * 192];
  __shared__ float hT[DD * HSTR];
  const int tid = threadIdx.x;
  for (int i = tid; i < DD * 192; i += 256) sW[i] = Whh[i];
  const int ct = tid & 15, rt = tid >> 4;
  const int d0 = ct * 4;
  const int row = blockIdx.x * 16 + rt;
  float bR[4], bZ[4], bN[4];
#pragma unroll
  for (int dd = 0; dd < 4; ++dd) {
    bR[dd] = bhh[d0 + dd];
    bZ[dd] = bhh[64 + d0 + dd];
    bN[dd] = bhh[128 + d0 + dd];
  }
  const int sl = seq_len[row];
  float h[4] = {0.f, 0.f, 0.f, 0.f};
  const us_t* gbase = gi + (long)row * TT * 192;
  ushort4 p0 = *(const ushort4*)(gbase + d0);
  ushort4 p1 = *(const ushort4*)(gbase + 64 + d0);
  ushort4 p2 = *(const ushort4*)(gbase + 128 + d0);
  __syncthreads();

  for (int t = 0; t < TT; ++t) {
#pragma unroll
    for (int dd = 0; dd < 4; ++dd) hT[(d0 + dd) * HSTR + rt] = h[dd];
    ushort4 n0, n1, n2;
    if (t + 1 < TT) {
      const us_t* gb = gbase + (long)(t + 1) * 192;
      n0 = *(const ushort4*)(gb + d0);
      n1 = *(const ushort4*)(gb + 64 + d0);
      n2 = *(const ushort4*)(gb + 128 + d0);
    }
    float aR[4], aZ[4], aN[4], aH[4];
    aR[0] = bR[0] + bf2f(p0.x); aR[1] = bR[1] + bf2f(p0.y);
    aR[2] = bR[2] + bf2f(p0.z); aR[3] = bR[3] + bf2f(p0.w);
    aZ[0] = bZ[0] + bf2f(p1.x); aZ[1] = bZ[1] + bf2f(p1.y);
    aZ[2] = bZ[2] + bf2f(p1.z); aZ[3] = bZ[3] + bf2f(p1.w);
    aN[0] = bf2f(p2.x); aN[1] = bf2f(p2.y);
    aN[2] = bf2f(p2.z); aN[3] = bf2f(p2.w);
#pragma unroll
    for (int dd = 0; dd < 4; ++dd) aH[dd] = bN[dd];
    __syncthreads();
#pragma unroll
    for (int k = 0; k < DD; ++k) {
      float hv = hT[k * HSTR + rt];
      const float* wr = &sW[k * 192 + d0];
      float w_r[4], w_z[4], w_n[4];
      *(float4*)w_r = *(const float4*)(wr);
      *(float4*)w_z = *(const float4*)(wr + 64);
      *(float4*)w_n = *(const float4*)(wr + 128);
#pragma unroll
      for (int dd = 0; dd < 4; ++dd) {
        aR[dd] = fmaf(hv, w_r[dd], aR[dd]);
        aZ[dd] = fmaf(hv, w_z[dd], aZ[dd]);
        aH[dd] = fmaf(hv, w_n[dd], aH[dd]);
      }
    }
    const bool m = t < sl;
#pragma unroll
    for (int dd = 0; dd < 4; ++dd) {
      float rg = 1.f / (1.f + __expf(-aR[dd]));
      float zg = 1.f / (1.f + __expf(-aZ[dd]));
      float ng = tanhf(fmaf(rg, aH[dd], aN[dd]));
      float hn = fmaf(zg, h[dd] - ng, ng);
      h[dd] = m ? hn : h[dd];
    }
    p0 = n0; p1 = n1; p2 = n2;
    __syncthreads();
  }
#pragma unroll
  for (int dd = 0; dd < 4; ++dd) hfin[(long)row * DD + d0 + dd] = h[dd];
}

// ---------------- final scoring ----------------

__global__ __launch_bounds__(256) void final_score(
    const float* __restrict__ u_sel, const float* __restrict__ itf,
    const float* __restrict__ hfin, const float* __restrict__ ln_g,
    const float* __restrict__ ln_b, const int* __restrict__ pos_idx,
    const int* __restrict__ neg_idx, const int* __restrict__ pos_beh,
    float* __restrict__ out) {
  __shared__ float partial[4];
  const int lane = threadIdx.x & 63;
  const int wv = threadIdx.x >> 6;
  const float g = ln_g[lane], bo = ln_b[lane];
  float local = 0.f;
  int wid = blockIdx.x * 4 + wv;
  int nw = gridDim.x * 4;
  for (int r = wid; r < BB; r += nw) {
    float uf = u_sel[(long)r * DD + lane] + hfin[(long)r * DD + lane];
    float mu = wave_sum64(uf) * (1.f / DD);
    float xc = uf - mu;
    float var = wave_sum64(xc * xc) * (1.f / DD);
    float un = xc * rsqrtf(var + LN_EPS_) * g + bo;
    float pv = itf[(long)pos_idx[r] * DD + lane];
    float nv = itf[(long)neg_idx[r] * DD + lane];
    float ps = wave_sum64(un * pv);
    float ns = wave_sum64(un * nv);
    float n1 = wave_sum64(un * un);
    float n2 = wave_sum64(pv * pv);
    float n3 = wave_sum64(nv * nv);
    float d = ps - ns;
    float sp = fmaxf(-d, 0.f) + log1pf(__expf(-fabsf(d)));
    int pb = pos_beh[r];
    pb = pb < 0 ? 0 : (pb > 3 ? 3 : pb);
    float bw = pb == 0 ? 1.0f : (pb == 1 ? 1.25f : (pb == 2 ? 1.6f : 2.1f));
    local += sp * bw + REG_COEF_ * (sqrtf(n1) + sqrtf(n2) + sqrtf(n3));
  }
  if (lane == 0) partial[wv] = local;
  __syncthreads();
  if (threadIdx.x == 0) {
    float s = partial[0] + partial[1] + partial[2] + partial[3];
    atomicAdd(out, s * (1.f / BB));
  }
}

extern "C" void kernel_launch(void* const* d_in, const int* in_sizes, int n_in,
                              void* d_out, int out_size, void* d_ws,
                              size_t ws_size, hipStream_t stream) {
  const float* user_emb = (const float*)d_in[0];
  const float* item_emb = (const float*)d_in[1];
  const float* beh_emb = (const float*)d_in[2];
  const float* t_w1 = (const float*)d_in[3];
  const float* t_b1 = (const float*)d_in[4];
  const float* t_w2 = (const float*)d_in[5];
  const float* t_b2 = (const float*)d_in[6];
  const float* gru_w_ih = (const float*)d_in[7];
  const float* gru_w_hh = (const float*)d_in[8];
  const float* gru_b_ih = (const float*)d_in[9];
  const float* gru_b_hh = (const float*)d_in[10];
  const float* gnn_user_w = (const float*)d_in[11];
  const float* gnn_user_b = (const float*)d_in[12];
  const float* gnn_item_w = (const float*)d_in[13];
  const float* gnn_item_b = (const float*)d_in[14];
  const float* ln_g = (const float*)d_in[15];
  const float* ln_b = (const float*)d_in[16];
  const float* ui_vals = (const float*)d_in[17];
  const float* adj_vals = (const float*)d_in[18];
  const float* seq_delta = (const float*)d_in[19];
  const int* ui_rows = (const int*)d_in[20];
  const int* ui_cols = (const int*)d_in[21];
  const int* adj_rows = (const int*)d_in[22];
  const int* adj_cols = (const int*)d_in[23];
  const int* seq_items = (const int*)d_in[24];
  const int* seq_behaviors = (const int*)d_in[25];
  const int* seq_len = (const int*)d_in[26];
  const int* user_idx = (const int*)d_in[27];
  const int* pos_item_idx = (const int*)d_in[28];
  const int* neg_item_idx = (const int*)d_in[29];
  const int* pos_behavior = (const int*)d_in[30];

  // ---- workspace layout ----
  float* ws = (float*)d_ws;
  float* u_a = ws;                               // U*64
  float* it_a = u_a + (long)U_N * DD;            // I*64
  float* it_b = it_a + (long)I_N * DD;           // I*64
  float* hfin = it_b + (long)I_N * DD;           // B*64
  float* u_sel = hfin + (long)BB * DD;           // B*64
  float* end_f = u_sel + (long)BB * DD;

  int2* pairs_ui_row = (int2*)end_f;             // EUI
  int2* pairs_ui_col = pairs_ui_row + N_EUI;     // EUI
  int2* pairs_adj = pairs_ui_col + N_EUI;        // EII

  us_t* gi = (us_t*)(pairs_adj + N_EII);         // B*T*192
  us_t* user_bf = gi + (long)BB * TT * 192;      // U*64
  us_t* item_bf = user_bf + (long)U_N * DD;      // I*64
  us_t* ua_bf = item_bf + (long)I_N * DD;        // U*64
  us_t* ita_bf = ua_bf + (long)U_N * DD;         // I*64

  int* offs_ui_row = (int*)(ita_bf + (long)I_N * DD);
  int* offs_ui_col = offs_ui_row + (U_N + 1);
  int* offs_adj = offs_ui_col + (I_N + 1);
  int* cur_ui_row = offs_adj + (I_N + 1);
  int* cur_ui_col = cur_ui_row + U_N;
  int* cur_adj = cur_ui_col + I_N;

  hipMemsetAsync(d_out, 0, (size_t)out_size * sizeof(float), stream);
  hipMemsetAsync(cur_ui_row, 0, (size_t)(U_N + I_N + I_N) * sizeof(int),
                 stream);

  // ---- bf16 copies of layer-0 gather sources ----
  to_bf16<<<1024, 256, 0, stream>>>(user_emb, user_bf, (long)U_N * DD / 4);
  to_bf16<<<1024, 256, 0, stream>>>(item_emb, item_bf, (long)I_N * DD / 4);

  // ---- CSR build ----
  hist_kernel<<<2048, 256, 0, stream>>>(ui_rows, N_EUI, cur_ui_row);
  hist_kernel<<<2048, 256, 0, stream>>>(ui_cols, N_EUI, cur_ui_col);
  hist_kernel<<<1024, 256, 0, stream>>>(adj_rows, N_EII, cur_adj);
  ex_scan<<<1, 1024, 0, stream>>>(cur_ui_row, U_N, offs_ui_row, cur_ui_row);
  ex_scan<<<1, 1024, 0, stream>>>(cur_ui_col, I_N, offs_ui_col, cur_ui_col);
  ex_scan<<<1, 1024, 0, stream>>>(cur_adj, I_N, offs_adj, cur_adj);
  csr_fill<<<2048, 256, 0, stream>>>(ui_rows, ui_cols, ui_vals, N_EUI,
                                     cur_ui_row, pairs_ui_row);
  csr_fill<<<2048, 256, 0, stream>>>(ui_cols, ui_rows, ui_vals, N_EUI,
                                     cur_ui_col, pairs_ui_col);
  csr_fill<<<1024, 256, 0, stream>>>(adj_rows, adj_cols, adj_vals, N_EII,
                                     cur_adj, pairs_adj);

  // ---- GNN layer 0 (dual-write f32 + bf16) ----
  gnn_user_layer<<<2048, 256, 0, stream>>>(user_emb, item_bf, offs_ui_row,
                                           pairs_ui_row, gnn_user_w,
                                           gnn_user_b, u_a, ua_bf);
  gnn_item_layer<<<2048, 256, 0, stream>>>(item_emb, item_bf, user_bf,
                                           offs_adj, pairs_adj, offs_ui_col,
                                           pairs_ui_col, gnn_item_w,
                                           gnn_item_b, it_a, ita_bf);
  // ---- GNN layer 1 (all items; users only where needed) ----
  gnn_item_layer<<<2048, 256, 0, stream>>>(it_a, ita_bf, ua_bf, offs_adj,
                                           pairs_adj, offs_ui_col,
                                           pairs_ui_col, gnn_item_w + DD * DD,
                                           gnn_item_b + DD, it_b, nullptr);
  gnn_user_sel<<<512, 256, 0, stream>>>(u_a, ita_bf, user_idx, offs_ui_row,
                                        pairs_ui_row, gnn_user_w + DD * DD,
                                        gnn_user_b + DD, u_sel);

  // ---- sequence encoding + gi precompute ----
  seq_encode_gi<<<2048, 256, 0, stream>>>(it_b, beh_emb, t_w1, t_b1, t_w2,
                                          t_b2, ln_g, ln_b, gru_w_ih,
                                          gru_b_ih, seq_delta, seq_items,
                                          seq_behaviors, gi);

  // ---- GRU scan (hh-half only) ----
  gru_scan3<<<BB / 16, 256, 0, stream>>>(gi, gru_w_hh, gru_b_hh, seq_len,
                                         hfin);

  // ---- final scoring ----
  final_score<<<256, 256, 0, stream>>>(u_sel, it_b, hfin, ln_g, ln_b,
                                       pos_item_idx, neg_item_idx,
                                       pos_behavior, (float*)d_out);
}

// Round 6
// 2167.374 us; speedup vs baseline: 3.0407x; 3.0407x over previous
//
#include <hip/hip_runtime.h>
#include <math.h>

#define U_N 100000
#define I_N 50000
#define DD  64
#define BB  8192
#define TT  30
#define N_EUI 1600000
#define N_EII 800000
#define LN_EPS_ 1e-5f
#define BEH_SCALE_ 0.35f
#define REG_COEF_ 1e-4f

typedef unsigned short us_t;

__device__ __forceinline__ float wave_sum64(float v) {
#pragma unroll
  for (int o = 32; o > 0; o >>= 1) v += __shfl_xor(v, o, 64);
  return v;
}

__device__ __forceinline__ float rdlane(float v, int k) {
  return __int_as_float(__builtin_amdgcn_readlane(__float_as_int(v), k));
}

__device__ __forceinline__ us_t f2bf(float f) {
  unsigned u = __float_as_uint(f);
  u += 0x7fffu + ((u >> 16) & 1u);
  return (us_t)(u >> 16);
}
__device__ __forceinline__ float bf2f(us_t h) {
  return __uint_as_float((unsigned)h << 16);
}

__device__ __forceinline__ void fma4(float* acc, float s, float4 w4) {
  acc[0] = fmaf(s, w4.x, acc[0]);
  acc[1] = fmaf(s, w4.y, acc[1]);
  acc[2] = fmaf(s, w4.z, acc[2]);
  acc[3] = fmaf(s, w4.w, acc[3]);
}

// ---------------- f32 -> bf16 table conversion ----------------
__global__ __launch_bounds__(256) void to_bf16(const float* __restrict__ in,
                                               us_t* __restrict__ out,
                                               long n4) {
  for (long i = (long)blockIdx.x * blockDim.x + threadIdx.x; i < n4;
       i += (long)gridDim.x * blockDim.x) {
    float4 f = ((const float4*)in)[i];
    ushort4 o;
    o.x = f2bf(f.x); o.y = f2bf(f.y); o.z = f2bf(f.z); o.w = f2bf(f.w);
    ((ushort4*)out)[i] = o;
  }
}

// ---------------- CSR build ----------------

__global__ __launch_bounds__(256) void hist_kernel(
    const int* __restrict__ rows, int nE, int* __restrict__ cnt) {
  for (long e = (long)blockIdx.x * blockDim.x + threadIdx.x; e < nE;
       e += (long)gridDim.x * blockDim.x)
    atomicAdd(&cnt[rows[e]], 1);
}

__global__ __launch_bounds__(1024) void ex_scan(
    const int* __restrict__ cnt, int n, int* __restrict__ offs,
    int* __restrict__ cursor) {
  __shared__ int part[1024];
  const int tid = threadIdx.x;
  const int chunk = (n + 1023) / 1024;
  const int lo = tid * chunk;
  const int hi = min(lo + chunk, n);
  int s = 0;
  for (int i = lo; i < hi; ++i) s += cnt[i];
  part[tid] = s;
  __syncthreads();
  for (int off = 1; off < 1024; off <<= 1) {
    int v = part[tid];
    int add = (tid >= off) ? part[tid - off] : 0;
    __syncthreads();
    part[tid] = v + add;
    __syncthreads();
  }
  int base = (tid == 0) ? 0 : part[tid - 1];
  for (int i = lo; i < hi; ++i) {
    int c = cnt[i];  // read BEFORE writing (cnt aliases cursor)
    offs[i] = base;
    cursor[i] = base;
    base += c;
  }
  if (tid == 0) offs[n] = part[1023];
}

__global__ __launch_bounds__(256) void csr_fill(
    const int* __restrict__ drows, const int* __restrict__ srows,
    const float* __restrict__ vals, int nE, int* __restrict__ cursor,
    int2* __restrict__ pairs) {
  for (long e = (long)blockIdx.x * blockDim.x + threadIdx.x; e < nE;
       e += (long)gridDim.x * blockDim.x) {
    int d = drows[e];
    int pos = atomicAdd(&cursor[d], 1);
    pairs[pos] = make_int2(srows[e], __float_as_int(vals[e]));
  }
}

// ---------------- fused GNN layers (bf16 gather, f32 compute) ----------------

__global__ __launch_bounds__(256) void gnn_user_layer(
    const float* __restrict__ cur_u, const us_t* __restrict__ src_bf,
    const int* __restrict__ offs, const int2* __restrict__ pairs,
    const float* __restrict__ W, const float* __restrict__ bias,
    float* __restrict__ out, us_t* __restrict__ out_bf) {
  __shared__ float Wl[DD * DD];
  for (int i = threadIdx.x; i < DD * DD; i += blockDim.x) Wl[i] = W[i];
  __syncthreads();
  const int lane = threadIdx.x & 63;
  const float bn = bias[lane];
  long wid = ((long)blockIdx.x * blockDim.x + threadIdx.x) >> 6;
  long nw = ((long)gridDim.x * blockDim.x) >> 6;
  for (long r = wid; r < U_N; r += nw) {
    float acc = cur_u[r * DD + lane], acc2 = 0.f;
    int j = offs[r], j1 = offs[r + 1];
    for (; j + 1 < j1; j += 2) {
      int2 p0 = pairs[j], p1 = pairs[j + 1];
      acc = fmaf(__int_as_float(p0.y), bf2f(src_bf[(long)p0.x * DD + lane]), acc);
      acc2 = fmaf(__int_as_float(p1.y), bf2f(src_bf[(long)p1.x * DD + lane]), acc2);
    }
    if (j < j1) {
      int2 p = pairs[j];
      acc = fmaf(__int_as_float(p.y), bf2f(src_bf[(long)p.x * DD + lane]), acc);
    }
    acc += acc2;
    float y = bn;
#pragma unroll
    for (int k = 0; k < DD; ++k)
      y = fmaf(rdlane(acc, k), Wl[k * DD + lane], y);
    y = fmaxf(y, 0.f);
    out[r * DD + lane] = y;
    if (out_bf) out_bf[r * DD + lane] = f2bf(y);
  }
}

__global__ __launch_bounds__(256) void gnn_item_layer(
    const float* __restrict__ cur_it, const us_t* __restrict__ it_bf,
    const us_t* __restrict__ u_bf, const int* __restrict__ offsA,
    const int2* __restrict__ pairsA, const int* __restrict__ offsB,
    const int2* __restrict__ pairsB, const float* __restrict__ W,
    const float* __restrict__ bias, float* __restrict__ out,
    us_t* __restrict__ out_bf) {
  __shared__ float Wl[DD * DD];
  for (int i = threadIdx.x; i < DD * DD; i += blockDim.x) Wl[i] = W[i];
  __syncthreads();
  const int lane = threadIdx.x & 63;
  const float bn = bias[lane];
  long wid = ((long)blockIdx.x * blockDim.x + threadIdx.x) >> 6;
  long nw = ((long)gridDim.x * blockDim.x) >> 6;
  for (long r = wid; r < I_N; r += nw) {
    float acc = cur_it[r * DD + lane], acc2 = 0.f;
    int j = offsA[r], j1 = offsA[r + 1];
    for (; j + 1 < j1; j += 2) {
      int2 p0 = pairsA[j], p1 = pairsA[j + 1];
      acc = fmaf(__int_as_float(p0.y), bf2f(it_bf[(long)p0.x * DD + lane]), acc);
      acc2 = fmaf(__int_as_float(p1.y), bf2f(it_bf[(long)p1.x * DD + lane]), acc2);
    }
    if (j < j1) {
      int2 p = pairsA[j];
      acc = fmaf(__int_as_float(p.y), bf2f(it_bf[(long)p.x * DD + lane]), acc);
    }
    j = offsB[r];
    j1 = offsB[r + 1];
    for (; j + 1 < j1; j += 2) {
      int2 p0 = pairsB[j], p1 = pairsB[j + 1];
      acc = fmaf(__int_as_float(p0.y), bf2f(u_bf[(long)p0.x * DD + lane]), acc);
      acc2 = fmaf(__int_as_float(p1.y), bf2f(u_bf[(long)p1.x * DD + lane]), acc2);
    }
    if (j < j1) {
      int2 p = pairsB[j];
      acc = fmaf(__int_as_float(p.y), bf2f(u_bf[(long)p.x * DD + lane]), acc);
    }
    acc += acc2;
    float y = bn;
#pragma unroll
    for (int k = 0; k < DD; ++k)
      y = fmaf(rdlane(acc, k), Wl[k * DD + lane], y);
    y = fmaxf(y, 0.f);
    out[r * DD + lane] = y;
    if (out_bf) out_bf[r * DD + lane] = f2bf(y);
  }
}

// layer-1 user output, only for the 8192 selected users
__global__ __launch_bounds__(256) void gnn_user_sel(
    const float* __restrict__ u_a, const us_t* __restrict__ ita_bf,
    const int* __restrict__ user_idx, const int* __restrict__ offs,
    const int2* __restrict__ pairs, const float* __restrict__ W,
    const float* __restrict__ bias, float* __restrict__ out) {
  __shared__ float Wl[DD * DD];
  for (int i = threadIdx.x; i < DD * DD; i += blockDim.x) Wl[i] = W[i];
  __syncthreads();
  const int lane = threadIdx.x & 63;
  const float bn = bias[lane];
  long wid = ((long)blockIdx.x * blockDim.x + threadIdx.x) >> 6;
  long nw = ((long)gridDim.x * blockDim.x) >> 6;
  for (long b = wid; b < BB; b += nw) {
    int r = user_idx[b];
    float acc = u_a[(long)r * DD + lane], acc2 = 0.f;
    int j = offs[r], j1 = offs[r + 1];
    for (; j + 1 < j1; j += 2) {
      int2 p0 = pairs[j], p1 = pairs[j + 1];
      acc = fmaf(__int_as_float(p0.y), bf2f(ita_bf[(long)p0.x * DD + lane]), acc);
      acc2 = fmaf(__int_as_float(p1.y), bf2f(ita_bf[(long)p1.x * DD + lane]), acc2);
    }
    if (j < j1) {
      int2 p = pairs[j];
      acc = fmaf(__int_as_float(p.y), bf2f(ita_bf[(long)p.x * DD + lane]), acc);
    }
    acc += acc2;
    float y = bn;
#pragma unroll
    for (int k = 0; k < DD; ++k)
      y = fmaf(rdlane(acc, k), Wl[k * DD + lane], y);
    out[b * DD + lane] = fmaxf(y, 0.f);
  }
}

// ------- seq encode + gi, 4 rows per wave, k-quad-transposed LDS weights -----
// W2q[(k>>2)*256 + c*4 + (k&3)] = t_w2[k][c]; WIq[(k>>2)*768 + c*4 + (k&3)] = Wih[k][c]

__global__ __launch_bounds__(256) void seq_encode_gi4(
    const float* __restrict__ itf, const float* __restrict__ beh_emb,
    const float* __restrict__ t_w1, const float* __restrict__ t_b1,
    const float* __restrict__ t_w2, const float* __restrict__ t_b2,
    const float* __restrict__ ln_g, const float* __restrict__ ln_b,
    const float* __restrict__ Wih, const float* __restrict__ bih,
    const float* __restrict__ delta, const int* __restrict__ items,
    const int* __restrict__ behs, us_t* __restrict__ gi) {
  __shared__ float W2q[DD * DD];    // 16 KB
  __shared__ float WIq[192 * DD];   // 48 KB
  for (int i = threadIdx.x; i < DD * DD; i += 256) {
    int k = i >> 6, c = i & 63;
    W2q[(k >> 2) * 256 + c * 4 + (k & 3)] = t_w2[i];
  }
  for (int i = threadIdx.x; i < DD * 192; i += 256) {
    int k = i / 192, c = i - k * 192;
    WIq[(k >> 2) * 768 + c * 4 + (k & 3)] = Wih[i];
  }
  __syncthreads();
  const int lane = threadIdx.x & 63;
  const float w1 = t_w1[lane], b1 = t_b1[lane], b2 = t_b2[lane];
  const float g = ln_g[lane], bo = ln_b[lane];
  const float bi0 = bih[lane], bi1 = bih[64 + lane], bi2 = bih[128 + lane];
  long wid = ((long)blockIdx.x * blockDim.x + threadIdx.x) >> 6;
  long nw = ((long)gridDim.x * blockDim.x) >> 6;
  const long NR = (long)BB * TT;
  for (long r4 = wid * 4; r4 < NR; r4 += nw * 4) {
    float xv[4], tmp[4];
#pragma unroll
    for (int i = 0; i < 4; ++i) {
      long r = r4 + i;
      int it = items[r];
      int bh = behs[r];
      xv[i] = itf[(long)it * DD + lane] + BEH_SCALE_ * beh_emb[bh * DD + lane];
      float tv = log1pf(delta[r]);
      tmp[i] = fmaxf(fmaf(tv, w1, b1), 0.f);
    }
    float y[4] = {b2, b2, b2, b2};
#pragma unroll 4
    for (int k4 = 0; k4 < 16; ++k4) {
      float4 w4 = *(const float4*)&W2q[k4 * 256 + lane * 4];
#pragma unroll
      for (int i = 0; i < 4; ++i) {
        y[i] = fmaf(rdlane(tmp[i], 4 * k4 + 0), w4.x, y[i]);
        y[i] = fmaf(rdlane(tmp[i], 4 * k4 + 1), w4.y, y[i]);
        y[i] = fmaf(rdlane(tmp[i], 4 * k4 + 2), w4.z, y[i]);
        y[i] = fmaf(rdlane(tmp[i], 4 * k4 + 3), w4.w, y[i]);
      }
    }
    float xo[4];
#pragma unroll
    for (int i = 0; i < 4; ++i) {
      float x = xv[i] + y[i];
      float mu = wave_sum64(x) * (1.f / DD);
      float xc = x - mu;
      float var = wave_sum64(xc * xc) * (1.f / DD);
      xo[i] = xc * rsqrtf(var + LN_EPS_) * g + bo;
    }
    float gA[4] = {bi0, bi0, bi0, bi0};
    float gB[4] = {bi1, bi1, bi1, bi1};
    float gC[4] = {bi2, bi2, bi2, bi2};
#pragma unroll 4
    for (int k4 = 0; k4 < 16; ++k4) {
      float4 wA = *(const float4*)&WIq[k4 * 768 + lane * 4];
      float4 wB = *(const float4*)&WIq[k4 * 768 + (64 + lane) * 4];
      float4 wC = *(const float4*)&WIq[k4 * 768 + (128 + lane) * 4];
#pragma unroll
      for (int i = 0; i < 4; ++i) {
        float s0 = rdlane(xo[i], 4 * k4 + 0);
        float s1 = rdlane(xo[i], 4 * k4 + 1);
        float s2 = rdlane(xo[i], 4 * k4 + 2);
        float s3 = rdlane(xo[i], 4 * k4 + 3);
        gA[i] = fmaf(s0, wA.x, gA[i]); gA[i] = fmaf(s1, wA.y, gA[i]);
        gA[i] = fmaf(s2, wA.z, gA[i]); gA[i] = fmaf(s3, wA.w, gA[i]);
        gB[i] = fmaf(s0, wB.x, gB[i]); gB[i] = fmaf(s1, wB.y, gB[i]);
        gB[i] = fmaf(s2, wB.z, gB[i]); gB[i] = fmaf(s3, wB.w, gB[i]);
        gC[i] = fmaf(s0, wC.x, gC[i]); gC[i] = fmaf(s1, wC.y, gC[i]);
        gC[i] = fmaf(s2, wC.z, gC[i]); gC[i] = fmaf(s3, wC.w, gC[i]);
      }
    }
#pragma unroll
    for (int i = 0; i < 4; ++i) {
      us_t* go = gi + (r4 + i) * 192;
      go[lane] = f2bf(gA[i]);
      go[64 + lane] = f2bf(gB[i]);
      go[128 + lane] = f2bf(gC[i]);
    }
  }
}

// ---------------- GRU scan v4: hh-half only, 32 rows/block ----------------
// Thread (ct=tid&15, rt=tid>>4) owns rows {r0,r0+1}, dims d0..d0+3 per gate.
#define GHSTR 34

__global__ __launch_bounds__(256, 4) void gru_scan4(
    const us_t* __restrict__ gi, const float* __restrict__ Whh,
    const float* __restrict__ bhh, const int* __restrict__ seq_len,
    float* __restrict__ hfin) {
  __shared__ float sW[DD * 192];       // 48 KB
  __shared__ float hT[DD * GHSTR];     // 8.7 KB
  const int tid = threadIdx.x;
  for (int i = tid; i < DD * 192; i += 256) sW[i] = Whh[i];
  const int ct = tid & 15, rt = tid >> 4;
  const int d0 = ct * 4, r0 = rt * 2;
  const int row0 = blockIdx.x * 32;
  float bR[4], bZ[4], bN[4];
#pragma unroll
  for (int dd = 0; dd < 4; ++dd) {
    bR[dd] = bhh[d0 + dd];
    bZ[dd] = bhh[64 + d0 + dd];
    bN[dd] = bhh[128 + d0 + dd];
  }
  const int sl0 = seq_len[row0 + r0], sl1 = seq_len[row0 + r0 + 1];
  float h0[4] = {0.f, 0.f, 0.f, 0.f}, h1[4] = {0.f, 0.f, 0.f, 0.f};
  const us_t* ga = gi + (long)(row0 + r0) * TT * 192;
  const us_t* gb = gi + (long)(row0 + r0 + 1) * TT * 192;
  ushort4 pa0 = *(const ushort4*)(ga + d0);
  ushort4 pa1 = *(const ushort4*)(ga + 64 + d0);
  ushort4 pa2 = *(const ushort4*)(ga + 128 + d0);
  ushort4 pb0 = *(const ushort4*)(gb + d0);
  ushort4 pb1 = *(const ushort4*)(gb + 64 + d0);
  ushort4 pb2 = *(const ushort4*)(gb + 128 + d0);
  __syncthreads();

  for (int t = 0; t < TT; ++t) {
#pragma unroll
    for (int dd = 0; dd < 4; ++dd) {
      hT[(d0 + dd) * GHSTR + r0] = h0[dd];
      hT[(d0 + dd) * GHSTR + r0 + 1] = h1[dd];
    }
    ushort4 na0, na1, na2, nb0, nb1, nb2;
    if (t + 1 < TT) {
      const us_t* a = ga + (long)(t + 1) * 192;
      const us_t* b = gb + (long)(t + 1) * 192;
      na0 = *(const ushort4*)(a + d0);
      na1 = *(const ushort4*)(a + 64 + d0);
      na2 = *(const ushort4*)(a + 128 + d0);
      nb0 = *(const ushort4*)(b + d0);
      nb1 = *(const ushort4*)(b + 64 + d0);
      nb2 = *(const ushort4*)(b + 128 + d0);
    }
    float aR0[4], aZ0[4], aN0[4], aH0[4];
    float aR1[4], aZ1[4], aN1[4], aH1[4];
    aR0[0] = bR[0] + bf2f(pa0.x); aR0[1] = bR[1] + bf2f(pa0.y);
    aR0[2] = bR[2] + bf2f(pa0.z); aR0[3] = bR[3] + bf2f(pa0.w);
    aZ0[0] = bZ[0] + bf2f(pa1.x); aZ0[1] = bZ[1] + bf2f(pa1.y);
    aZ0[2] = bZ[2] + bf2f(pa1.z); aZ0[3] = bZ[3] + bf2f(pa1.w);
    aN0[0] = bf2f(pa2.x); aN0[1] = bf2f(pa2.y);
    aN0[2] = bf2f(pa2.z); aN0[3] = bf2f(pa2.w);
    aR1[0] = bR[0] + bf2f(pb0.x); aR1[1] = bR[1] + bf2f(pb0.y);
    aR1[2] = bR[2] + bf2f(pb0.z); aR1[3] = bR[3] + bf2f(pb0.w);
    aZ1[0] = bZ[0] + bf2f(pb1.x); aZ1[1] = bZ[1] + bf2f(pb1.y);
    aZ1[2] = bZ[2] + bf2f(pb1.z); aZ1[3] = bZ[3] + bf2f(pb1.w);
    aN1[0] = bf2f(pb2.x); aN1[1] = bf2f(pb2.y);
    aN1[2] = bf2f(pb2.z); aN1[3] = bf2f(pb2.w);
#pragma unroll
    for (int dd = 0; dd < 4; ++dd) {
      aH0[dd] = bN[dd];
      aH1[dd] = bN[dd];
    }
    __syncthreads();
#pragma unroll 8
    for (int k = 0; k < DD; ++k) {
      float2 hh = *(const float2*)&hT[k * GHSTR + r0];
      float4 wr4 = *(const float4*)&sW[k * 192 + d0];
      float4 wz4 = *(const float4*)&sW[k * 192 + 64 + d0];
      float4 wn4 = *(const float4*)&sW[k * 192 + 128 + d0];
      fma4(aR0, hh.x, wr4);
      fma4(aR1, hh.y, wr4);
      fma4(aZ0, hh.x, wz4);
      fma4(aZ1, hh.y, wz4);
      fma4(aH0, hh.x, wn4);
      fma4(aH1, hh.y, wn4);
    }
    const bool m0 = t < sl0, m1 = t < sl1;
#pragma unroll
    for (int dd = 0; dd < 4; ++dd) {
      float rg = 1.f / (1.f + __expf(-aR0[dd]));
      float zg = 1.f / (1.f + __expf(-aZ0[dd]));
      float ng = tanhf(fmaf(rg, aH0[dd], aN0[dd]));
      float hn = fmaf(zg, h0[dd] - ng, ng);
      h0[dd] = m0 ? hn : h0[dd];
      rg = 1.f / (1.f + __expf(-aR1[dd]));
      zg = 1.f / (1.f + __expf(-aZ1[dd]));
      ng = tanhf(fmaf(rg, aH1[dd], aN1[dd]));
      hn = fmaf(zg, h1[dd] - ng, ng);
      h1[dd] = m1 ? hn : h1[dd];
    }
    pa0 = na0; pa1 = na1; pa2 = na2;
    pb0 = nb0; pb1 = nb1; pb2 = nb2;
    __syncthreads();
  }
#pragma unroll
  for (int dd = 0; dd < 4; ++dd) {
    hfin[(long)(row0 + r0) * DD + d0 + dd] = h0[dd];
    hfin[(long)(row0 + r0 + 1) * DD + d0 + dd] = h1[dd];
  }
}

// ---------------- final scoring ----------------

__global__ __launch_bounds__(256) void final_score(
    const float* __restrict__ u_sel, const float* __restrict__ itf,
    const float* __restrict__ hfin, const float* __restrict__ ln_g,
    const float* __restrict__ ln_b, const int* __restrict__ pos_idx,
    const int* __restrict__ neg_idx, const int* __restrict__ pos_beh,
    float* __restrict__ out) {
  __shared__ float partial[4];
  const int lane = threadIdx.x & 63;
  const int wv = threadIdx.x >> 6;
  const float g = ln_g[lane], bo = ln_b[lane];
  float local = 0.f;
  int wid = blockIdx.x * 4 + wv;
  int nw = gridDim.x * 4;
  for (int r = wid; r < BB; r += nw) {
    float uf = u_sel[(long)r * DD + lane] + hfin[(long)r * DD + lane];
    float mu = wave_sum64(uf) * (1.f / DD);
    float xc = uf - mu;
    float var = wave_sum64(xc * xc) * (1.f / DD);
    float un = xc * rsqrtf(var + LN_EPS_) * g + bo;
    float pv = itf[(long)pos_idx[r] * DD + lane];
    float nv = itf[(long)neg_idx[r] * DD + lane];
    float ps = wave_sum64(un * pv);
    float ns = wave_sum64(un * nv);
    float n1 = wave_sum64(un * un);
    float n2 = wave_sum64(pv * pv);
    float n3 = wave_sum64(nv * nv);
    float d = ps - ns;
    float sp = fmaxf(-d, 0.f) + log1pf(__expf(-fabsf(d)));
    int pb = pos_beh[r];
    pb = pb < 0 ? 0 : (pb > 3 ? 3 : pb);
    float bw = pb == 0 ? 1.0f : (pb == 1 ? 1.25f : (pb == 2 ? 1.6f : 2.1f));
    local += sp * bw + REG_COEF_ * (sqrtf(n1) + sqrtf(n2) + sqrtf(n3));
  }
  if (lane == 0) partial[wv] = local;
  __syncthreads();
  if (threadIdx.x == 0) {
    float s = partial[0] + partial[1] + partial[2] + partial[3];
    atomicAdd(out, s * (1.f / BB));
  }
}

extern "C" void kernel_launch(void* const* d_in, const int* in_sizes, int n_in,
                              void* d_out, int out_size, void* d_ws,
                              size_t ws_size, hipStream_t stream) {
  const float* user_emb = (const float*)d_in[0];
  const float* item_emb = (const float*)d_in[1];
  const float* beh_emb = (const float*)d_in[2];
  const float* t_w1 = (const float*)d_in[3];
  const float* t_b1 = (const float*)d_in[4];
  const float* t_w2 = (const float*)d_in[5];
  const float* t_b2 = (const float*)d_in[6];
  const float* gru_w_ih = (const float*)d_in[7];
  const float* gru_w_hh = (const float*)d_in[8];
  const float* gru_b_ih = (const float*)d_in[9];
  const float* gru_b_hh = (const float*)d_in[10];
  const float* gnn_user_w = (const float*)d_in[11];
  const float* gnn_user_b = (const float*)d_in[12];
  const float* gnn_item_w = (const float*)d_in[13];
  const float* gnn_item_b = (const float*)d_in[14];
  const float* ln_g = (const float*)d_in[15];
  const float* ln_b = (const float*)d_in[16];
  const float* ui_vals = (const float*)d_in[17];
  const float* adj_vals = (const float*)d_in[18];
  const float* seq_delta = (const float*)d_in[19];
  const int* ui_rows = (const int*)d_in[20];
  const int* ui_cols = (const int*)d_in[21];
  const int* adj_rows = (const int*)d_in[22];
  const int* adj_cols = (const int*)d_in[23];
  const int* seq_items = (const int*)d_in[24];
  const int* seq_behaviors = (const int*)d_in[25];
  const int* seq_len = (const int*)d_in[26];
  const int* user_idx = (const int*)d_in[27];
  const int* pos_item_idx = (const int*)d_in[28];
  const int* neg_item_idx = (const int*)d_in[29];
  const int* pos_behavior = (const int*)d_in[30];

  // ---- workspace layout ----
  float* ws = (float*)d_ws;
  float* u_a = ws;                               // U*64
  float* it_a = u_a + (long)U_N * DD;            // I*64
  float* it_b = it_a + (long)I_N * DD;           // I*64
  float* hfin = it_b + (long)I_N * DD;           // B*64
  float* u_sel = hfin + (long)BB * DD;           // B*64
  float* end_f = u_sel + (long)BB * DD;

  int2* pairs_ui_row = (int2*)end_f;             // EUI
  int2* pairs_ui_col = pairs_ui_row + N_EUI;     // EUI
  int2* pairs_adj = pairs_ui_col + N_EUI;        // EII

  us_t* gi = (us_t*)(pairs_adj + N_EII);         // B*T*192
  us_t* user_bf = gi + (long)BB * TT * 192;      // U*64
  us_t* item_bf = user_bf + (long)U_N * DD;      // I*64
  us_t* ua_bf = item_bf + (long)I_N * DD;        // U*64
  us_t* ita_bf = ua_bf + (long)U_N * DD;         // I*64

  int* offs_ui_row = (int*)(ita_bf + (long)I_N * DD);
  int* offs_ui_col = offs_ui_row + (U_N + 1);
  int* offs_adj = offs_ui_col + (I_N + 1);
  int* cur_ui_row = offs_adj + (I_N + 1);
  int* cur_ui_col = cur_ui_row + U_N;
  int* cur_adj = cur_ui_col + I_N;

  hipMemsetAsync(d_out, 0, (size_t)out_size * sizeof(float), stream);
  hipMemsetAsync(cur_ui_row, 0, (size_t)(U_N + I_N + I_N) * sizeof(int),
                 stream);

  // ---- bf16 copies of layer-0 gather sources ----
  to_bf16<<<1024, 256, 0, stream>>>(user_emb, user_bf, (long)U_N * DD / 4);
  to_bf16<<<1024, 256, 0, stream>>>(item_emb, item_bf, (long)I_N * DD / 4);

  // ---- CSR build ----
  hist_kernel<<<2048, 256, 0, stream>>>(ui_rows, N_EUI, cur_ui_row);
  hist_kernel<<<2048, 256, 0, stream>>>(ui_cols, N_EUI, cur_ui_col);
  hist_kernel<<<1024, 256, 0, stream>>>(adj_rows, N_EII, cur_adj);
  ex_scan<<<1, 1024, 0, stream>>>(cur_ui_row, U_N, offs_ui_row, cur_ui_row);
  ex_scan<<<1, 1024, 0, stream>>>(cur_ui_col, I_N, offs_ui_col, cur_ui_col);
  ex_scan<<<1, 1024, 0, stream>>>(cur_adj, I_N, offs_adj, cur_adj);
  csr_fill<<<2048, 256, 0, stream>>>(ui_rows, ui_cols, ui_vals, N_EUI,
                                     cur_ui_row, pairs_ui_row);
  csr_fill<<<2048, 256, 0, stream>>>(ui_cols, ui_rows, ui_vals, N_EUI,
                                     cur_ui_col, pairs_ui_col);
  csr_fill<<<1024, 256, 0, stream>>>(adj_rows, adj_cols, adj_vals, N_EII,
                                     cur_adj, pairs_adj);

  // ---- GNN layer 0 (dual-write f32 + bf16) ----
  gnn_user_layer<<<2048, 256, 0, stream>>>(user_emb, item_bf, offs_ui_row,
                                           pairs_ui_row, gnn_user_w,
                                           gnn_user_b, u_a, ua_bf);
  gnn_item_layer<<<2048, 256, 0, stream>>>(item_emb, item_bf, user_bf,
                                           offs_adj, pairs_adj, offs_ui_col,
                                           pairs_ui_col, gnn_item_w,
                                           gnn_item_b, it_a, ita_bf);
  // ---- GNN layer 1 (all items; users only where needed) ----
  gnn_item_layer<<<2048, 256, 0, stream>>>(it_a, ita_bf, ua_bf, offs_adj,
                                           pairs_adj, offs_ui_col,
                                           pairs_ui_col, gnn_item_w + DD * DD,
                                           gnn_item_b + DD, it_b, nullptr);
  gnn_user_sel<<<512, 256, 0, stream>>>(u_a, ita_bf, user_idx, offs_ui_row,
                                        pairs_ui_row, gnn_user_w + DD * DD,
                                        gnn_user_b + DD, u_sel);

  // ---- sequence encoding + gi precompute ----
  seq_encode_gi4<<<512, 256, 0, stream>>>(it_b, beh_emb, t_w1, t_b1, t_w2,
                                          t_b2, ln_g, ln_b, gru_w_ih,
                                          gru_b_ih, seq_delta, seq_items,
                                          seq_behaviors, gi);

  // ---- GRU scan (hh-half only) ----
  gru_scan4<<<BB / 32, 256, 0, stream>>>(gi, gru_w_hh, gru_b_hh, seq_len,
                                         hfin);

  // ---- final scoring ----
  final_score<<<256, 256, 0, stream>>>(u_sel, it_b, hfin, ln_g, ln_b,
                                       pos_item_idx, neg_item_idx,
                                       pos_behavior, (float*)d_out);
}

// Round 7
// 1804.073 us; speedup vs baseline: 3.6530x; 1.2014x over previous
//
#include <hip/hip_runtime.h>
#include <math.h>

#define U_N 100000
#define I_N 50000
#define DD  64
#define BB  8192
#define TT  30
#define N_EUI 1600000
#define N_EII 800000
#define LN_EPS_ 1e-5f
#define BEH_SCALE_ 0.35f
#define REG_COEF_ 1e-4f

typedef unsigned short us_t;
typedef __attribute__((ext_vector_type(8))) short bf16x8;
typedef __attribute__((ext_vector_type(4))) float f32x4;

__device__ __forceinline__ float wave_sum64(float v) {
#pragma unroll
  for (int o = 32; o > 0; o >>= 1) v += __shfl_xor(v, o, 64);
  return v;
}

__device__ __forceinline__ float rdlane(float v, int k) {
  return __int_as_float(__builtin_amdgcn_readlane(__float_as_int(v), k));
}

__device__ __forceinline__ us_t f2bf(float f) {
  unsigned u = __float_as_uint(f);
  u += 0x7fffu + ((u >> 16) & 1u);
  return (us_t)(u >> 16);
}
__device__ __forceinline__ float bf2f(us_t h) {
  return __uint_as_float((unsigned)h << 16);
}

__device__ __forceinline__ void fma4(float* acc, float s, float4 w4) {
  acc[0] = fmaf(s, w4.x, acc[0]);
  acc[1] = fmaf(s, w4.y, acc[1]);
  acc[2] = fmaf(s, w4.z, acc[2]);
  acc[3] = fmaf(s, w4.w, acc[3]);
}

// ---------------- f32 -> bf16 table conversion ----------------
__global__ __launch_bounds__(256) void to_bf16(const float* __restrict__ in,
                                               us_t* __restrict__ out,
                                               long n4) {
  for (long i = (long)blockIdx.x * blockDim.x + threadIdx.x; i < n4;
       i += (long)gridDim.x * blockDim.x) {
    float4 f = ((const float4*)in)[i];
    ushort4 o;
    o.x = f2bf(f.x); o.y = f2bf(f.y); o.z = f2bf(f.z); o.w = f2bf(f.w);
    ((ushort4*)out)[i] = o;
  }
}

// ---------------- CSR build (merged kernels) ----------------

// blocks [0,1024): ui_rows -> c0 ; [1024,2048): ui_cols -> c1 ; [2048,2560): adj_rows -> c2
__global__ __launch_bounds__(256) void hist3(
    const int* __restrict__ r0, const int* __restrict__ r1,
    const int* __restrict__ r2, int* __restrict__ c0, int* __restrict__ c1,
    int* __restrict__ c2) {
  int b = blockIdx.x;
  const int* rows; int* cnt; int n, base, nb;
  if (b < 1024) { rows = r0; cnt = c0; n = N_EUI; base = 0; nb = 1024; }
  else if (b < 2048) { rows = r1; cnt = c1; n = N_EUI; base = 1024; nb = 1024; }
  else { rows = r2; cnt = c2; n = N_EII; base = 2048; nb = 512; }
  for (long e = (long)(b - base) * 256 + threadIdx.x; e < n;
       e += (long)nb * 256)
    atomicAdd(&cnt[rows[e]], 1);
}

__device__ __forceinline__ void ex_scan_body(const int* cnt, int n, int* offs,
                                             int* cursor, int* part) {
  const int tid = threadIdx.x;
  const int chunk = (n + 1023) / 1024;
  const int lo = tid * chunk;
  const int hi = min(lo + chunk, n);
  int s = 0;
  for (int i = lo; i < hi; ++i) s += cnt[i];
  part[tid] = s;
  __syncthreads();
  for (int off = 1; off < 1024; off <<= 1) {
    int v = part[tid];
    int add = (tid >= off) ? part[tid - off] : 0;
    __syncthreads();
    part[tid] = v + add;
    __syncthreads();
  }
  int base = (tid == 0) ? 0 : part[tid - 1];
  for (int i = lo; i < hi; ++i) {
    int c = cnt[i];  // read BEFORE writing (cnt aliases cursor)
    offs[i] = base;
    cursor[i] = base;
    base += c;
  }
  if (tid == 0) offs[n] = part[1023];
}

// 3 blocks: one scan each
__global__ __launch_bounds__(1024) void scan3(
    int* __restrict__ c0, int* __restrict__ o0, int* __restrict__ c1,
    int* __restrict__ o1, int* __restrict__ c2, int* __restrict__ o2) {
  __shared__ int part[1024];
  if (blockIdx.x == 0) ex_scan_body(c0, U_N, o0, c0, part);
  else if (blockIdx.x == 1) ex_scan_body(c1, I_N, o1, c1, part);
  else ex_scan_body(c2, I_N, o2, c2, part);
}

__global__ __launch_bounds__(256) void fill3(
    const int* __restrict__ d0, const int* __restrict__ s0,
    const float* __restrict__ v0, int* __restrict__ cu0,
    int2* __restrict__ p0, const int* __restrict__ d1,
    const int* __restrict__ s1, const float* __restrict__ v1,
    int* __restrict__ cu1, int2* __restrict__ p1, const int* __restrict__ d2,
    const int* __restrict__ s2, const float* __restrict__ v2,
    int* __restrict__ cu2, int2* __restrict__ p2) {
  int b = blockIdx.x;
  const int *drows, *srows; const float* vals; int* cursor; int2* pairs;
  int n, base, nb;
  if (b < 1024) { drows = d0; srows = s0; vals = v0; cursor = cu0; pairs = p0;
                  n = N_EUI; base = 0; nb = 1024; }
  else if (b < 2048) { drows = d1; srows = s1; vals = v1; cursor = cu1;
                       pairs = p1; n = N_EUI; base = 1024; nb = 1024; }
  else { drows = d2; srows = s2; vals = v2; cursor = cu2; pairs = p2;
         n = N_EII; base = 2048; nb = 512; }
  for (long e = (long)(b - base) * 256 + threadIdx.x; e < n;
       e += (long)nb * 256) {
    int d = drows[e];
    int pos = atomicAdd(&cursor[d], 1);
    pairs[pos] = make_int2(srows[e], __float_as_int(vals[e]));
  }
}

// ---------------- fused GNN layers (bf16 gather, f32 compute) ----------------

__global__ __launch_bounds__(256) void gnn_user_layer(
    const float* __restrict__ cur_u, const us_t* __restrict__ src_bf,
    const int* __restrict__ offs, const int2* __restrict__ pairs,
    const float* __restrict__ W, const float* __restrict__ bias,
    float* __restrict__ out, us_t* __restrict__ out_bf) {
  __shared__ float Wl[DD * DD];
  for (int i = threadIdx.x; i < DD * DD; i += blockDim.x) Wl[i] = W[i];
  __syncthreads();
  const int lane = threadIdx.x & 63;
  const float bn = bias[lane];
  long wid = ((long)blockIdx.x * blockDim.x + threadIdx.x) >> 6;
  long nw = ((long)gridDim.x * blockDim.x) >> 6;
  for (long r = wid; r < U_N; r += nw) {
    float acc = cur_u[r * DD + lane], acc2 = 0.f;
    int j = offs[r], j1 = offs[r + 1];
    for (; j + 1 < j1; j += 2) {
      int2 p0 = pairs[j], p1 = pairs[j + 1];
      acc = fmaf(__int_as_float(p0.y), bf2f(src_bf[(long)p0.x * DD + lane]), acc);
      acc2 = fmaf(__int_as_float(p1.y), bf2f(src_bf[(long)p1.x * DD + lane]), acc2);
    }
    if (j < j1) {
      int2 p = pairs[j];
      acc = fmaf(__int_as_float(p.y), bf2f(src_bf[(long)p.x * DD + lane]), acc);
    }
    acc += acc2;
    float y = bn;
#pragma unroll
    for (int k = 0; k < DD; ++k)
      y = fmaf(rdlane(acc, k), Wl[k * DD + lane], y);
    y = fmaxf(y, 0.f);
    out[r * DD + lane] = y;
    if (out_bf) out_bf[r * DD + lane] = f2bf(y);
  }
}

__global__ __launch_bounds__(256) void gnn_item_layer(
    const float* __restrict__ cur_it, const us_t* __restrict__ it_bf,
    const us_t* __restrict__ u_bf, const int* __restrict__ offsA,
    const int2* __restrict__ pairsA, const int* __restrict__ offsB,
    const int2* __restrict__ pairsB, const float* __restrict__ W,
    const float* __restrict__ bias, float* __restrict__ out,
    us_t* __restrict__ out_bf) {
  __shared__ float Wl[DD * DD];
  for (int i = threadIdx.x; i < DD * DD; i += blockDim.x) Wl[i] = W[i];
  __syncthreads();
  const int lane = threadIdx.x & 63;
  const float bn = bias[lane];
  long wid = ((long)blockIdx.x * blockDim.x + threadIdx.x) >> 6;
  long nw = ((long)gridDim.x * blockDim.x) >> 6;
  for (long r = wid; r < I_N; r += nw) {
    float acc = cur_it[r * DD + lane], acc2 = 0.f;
    int j = offsA[r], j1 = offsA[r + 1];
    for (; j + 1 < j1; j += 2) {
      int2 p0 = pairsA[j], p1 = pairsA[j + 1];
      acc = fmaf(__int_as_float(p0.y), bf2f(it_bf[(long)p0.x * DD + lane]), acc);
      acc2 = fmaf(__int_as_float(p1.y), bf2f(it_bf[(long)p1.x * DD + lane]), acc2);
    }
    if (j < j1) {
      int2 p = pairsA[j];
      acc = fmaf(__int_as_float(p.y), bf2f(it_bf[(long)p.x * DD + lane]), acc);
    }
    j = offsB[r];
    j1 = offsB[r + 1];
    for (; j + 1 < j1; j += 2) {
      int2 p0 = pairsB[j], p1 = pairsB[j + 1];
      acc = fmaf(__int_as_float(p0.y), bf2f(u_bf[(long)p0.x * DD + lane]), acc);
      acc2 = fmaf(__int_as_float(p1.y), bf2f(u_bf[(long)p1.x * DD + lane]), acc2);
    }
    if (j < j1) {
      int2 p = pairsB[j];
      acc = fmaf(__int_as_float(p.y), bf2f(u_bf[(long)p.x * DD + lane]), acc);
    }
    acc += acc2;
    float y = bn;
#pragma unroll
    for (int k = 0; k < DD; ++k)
      y = fmaf(rdlane(acc, k), Wl[k * DD + lane], y);
    y = fmaxf(y, 0.f);
    out[r * DD + lane] = y;
    if (out_bf) out_bf[r * DD + lane] = f2bf(y);
  }
}

__global__ __launch_bounds__(256) void gnn_user_sel(
    const float* __restrict__ u_a, const us_t* __restrict__ ita_bf,
    const int* __restrict__ user_idx, const int* __restrict__ offs,
    const int2* __restrict__ pairs, const float* __restrict__ W,
    const float* __restrict__ bias, float* __restrict__ out) {
  __shared__ float Wl[DD * DD];
  for (int i = threadIdx.x; i < DD * DD; i += blockDim.x) Wl[i] = W[i];
  __syncthreads();
  const int lane = threadIdx.x & 63;
  const float bn = bias[lane];
  long wid = ((long)blockIdx.x * blockDim.x + threadIdx.x) >> 6;
  long nw = ((long)gridDim.x * blockDim.x) >> 6;
  for (long b = wid; b < BB; b += nw) {
    int r = user_idx[b];
    float acc = u_a[(long)r * DD + lane], acc2 = 0.f;
    int j = offs[r], j1 = offs[r + 1];
    for (; j + 1 < j1; j += 2) {
      int2 p0 = pairs[j], p1 = pairs[j + 1];
      acc = fmaf(__int_as_float(p0.y), bf2f(ita_bf[(long)p0.x * DD + lane]), acc);
      acc2 = fmaf(__int_as_float(p1.y), bf2f(ita_bf[(long)p1.x * DD + lane]), acc2);
    }
    if (j < j1) {
      int2 p = pairs[j];
      acc = fmaf(__int_as_float(p.y), bf2f(ita_bf[(long)p.x * DD + lane]), acc);
    }
    acc += acc2;
    float y = bn;
#pragma unroll
    for (int k = 0; k < DD; ++k)
      y = fmaf(rdlane(acc, k), Wl[k * DD + lane], y);
    out[b * DD + lane] = fmaxf(y, 0.f);
  }
}

// ---------------- seq encode + gi via MFMA ----------------
// Wave owns a 16-row tile. A-frag layout (16x16x32 bf16): lane l holds
// A[l&15][(l>>4)*8+j]; B: B[(l>>4)*8+j][l&15]; C/D: col=l&15, row=(l>>4)*4+reg
// (HW-verified). A-tiles in LDS with 16B-granular XOR swizzle (u ^= row&7).

__global__ __launch_bounds__(256) void seq_mfma(
    const float* __restrict__ itf, const float* __restrict__ beh_emb,
    const float* __restrict__ t_w1, const float* __restrict__ t_b1,
    const float* __restrict__ t_w2, const float* __restrict__ t_b2,
    const float* __restrict__ ln_g, const float* __restrict__ ln_b,
    const float* __restrict__ Wih, const float* __restrict__ bih,
    const float* __restrict__ delta, const int* __restrict__ items,
    const int* __restrict__ behs, us_t* __restrict__ gi) {
  __shared__ __attribute__((aligned(16))) us_t WB2s[8 * 512];    // 8 KB
  __shared__ __attribute__((aligned(16))) us_t WBIs[24 * 512];   // 24 KB
  __shared__ __attribute__((aligned(16))) us_t AFs[4][1024];     // 8 KB
  __shared__ __attribute__((aligned(16))) float yTs[4][16 * 68]; // 17 KB
  const int tid = threadIdx.x;
  // repack weights into B-fragment layout (bf16)
  for (int idx = tid; idx < 8 * 512; idx += 256) {
    int f = idx >> 9, l = (idx >> 3) & 63, j = idx & 7;
    int ct = f >> 1, kt = f & 1;
    int k = kt * 32 + ((l >> 4) << 3) + j;
    int c = (ct << 4) + (l & 15);
    WB2s[idx] = f2bf(t_w2[k * 64 + c]);
  }
  for (int idx = tid; idx < 24 * 512; idx += 256) {
    int f = idx >> 9, l = (idx >> 3) & 63, j = idx & 7;
    int ct = f >> 1, kt = f & 1;
    int k = kt * 32 + ((l >> 4) << 3) + j;
    int c = (ct << 4) + (l & 15);
    WBIs[idx] = f2bf(Wih[k * 192 + c]);
  }
  __syncthreads();

  const int lane = tid & 63;
  const int wv = tid >> 6;
  const float w1l = t_w1[lane], b1l = t_b1[lane], b2l = t_b2[lane];
  const float gl = ln_g[lane], bol = ln_b[lane];
  const int colL = lane & 15;
  const int rbase = (lane >> 4) * 4;
  float biv[12];
#pragma unroll
  for (int ct = 0; ct < 12; ++ct) biv[ct] = bih[ct * 16 + colL];

  us_t* AF = AFs[wv];
  float* yT = yTs[wv];
  const long wgl = (long)blockIdx.x * 4 + wv;   // 480*4 = 1920 waves

  // A-frag read offsets (us_t index), row = lane&15
  const int row = lane & 15;
  const int a_off0 = ((row * 8 + 0 + (lane >> 4)) ^ (row & 7)) * 8;
  const int a_off1 = ((row * 8 + 4 + (lane >> 4)) ^ (row & 7)) * 8;

  for (int it8 = 0; it8 < 8; ++it8) {               // 1920*8 = 15360 tiles
    const long tile = wgl * 8 + it8;
    const long r0 = tile * 16;
    // ---- phase A: gather x_base, compute tmp -> AF (A-frag bf16) ----
    float xbr[16];
#pragma unroll
    for (int r = 0; r < 16; ++r) {
      long ridx = r0 + r;
      int itm = items[ridx];
      int bh = behs[ridx];
      xbr[r] = itf[(long)itm * DD + lane] +
               BEH_SCALE_ * beh_emb[bh * DD + lane];
      float tv = log1pf(delta[ridx]);
      float tmp = fmaxf(fmaf(tv, w1l, b1l), 0.f);
      int u = (r * 8 + (lane >> 3)) ^ (r & 7);
      AF[u * 8 + (lane & 7)] = f2bf(tmp);
    }
    __syncthreads();
    // ---- MFMA: y = tmp @ W2 -> yT ----
    {
      bf16x8 aA = *(const bf16x8*)&AF[a_off0];
      bf16x8 aB = *(const bf16x8*)&AF[a_off1];
#pragma unroll
      for (int ct = 0; ct < 4; ++ct) {
        f32x4 acc = {0.f, 0.f, 0.f, 0.f};
        bf16x8 b0 = *(const bf16x8*)&WB2s[(ct * 2 + 0) * 512 + lane * 8];
        bf16x8 b1 = *(const bf16x8*)&WB2s[(ct * 2 + 1) * 512 + lane * 8];
        acc = __builtin_amdgcn_mfma_f32_16x16x32_bf16(aA, b0, acc, 0, 0, 0);
        acc = __builtin_amdgcn_mfma_f32_16x16x32_bf16(aB, b1, acc, 0, 0, 0);
        int col = ct * 16 + colL;
#pragma unroll
        for (int i = 0; i < 4; ++i) yT[(rbase + i) * 68 + col] = acc[i];
      }
    }
    __syncthreads();
    // ---- phase B: x = xb + y + b2 ; LN ; xo -> AF (A-frag bf16) ----
#pragma unroll
    for (int r = 0; r < 16; ++r) {
      float x = xbr[r] + yT[r * 68 + lane] + b2l;
      float mu = wave_sum64(x) * (1.f / DD);
      float xc = x - mu;
      float var = wave_sum64(xc * xc) * (1.f / DD);
      float xo = xc * rsqrtf(var + LN_EPS_) * gl + bol;
      int u = (r * 8 + (lane >> 3)) ^ (r & 7);
      AF[u * 8 + (lane & 7)] = f2bf(xo);
    }
    __syncthreads();
    // ---- MFMA: gi = xo @ Wih + bih -> global (bf16) ----
    {
      bf16x8 aA = *(const bf16x8*)&AF[a_off0];
      bf16x8 aB = *(const bf16x8*)&AF[a_off1];
      us_t* go = gi + r0 * 192;
#pragma unroll
      for (int ct = 0; ct < 12; ++ct) {
        float bv = biv[ct];
        f32x4 acc = {bv, bv, bv, bv};
        bf16x8 b0 = *(const bf16x8*)&WBIs[(ct * 2 + 0) * 512 + lane * 8];
        bf16x8 b1 = *(const bf16x8*)&WBIs[(ct * 2 + 1) * 512 + lane * 8];
        acc = __builtin_amdgcn_mfma_f32_16x16x32_bf16(aA, b0, acc, 0, 0, 0);
        acc = __builtin_amdgcn_mfma_f32_16x16x32_bf16(aB, b1, acc, 0, 0, 0);
#pragma unroll
        for (int i = 0; i < 4; ++i)
          go[(long)(rbase + i) * 192 + ct * 16 + colL] = f2bf(acc[i]);
      }
    }
    __syncthreads();
  }
}

// ---------------- GRU scan v4: hh-half only, 32 rows/block ----------------
#define GHSTR 34

__global__ __launch_bounds__(256, 4) void gru_scan4(
    const us_t* __restrict__ gi, const float* __restrict__ Whh,
    const float* __restrict__ bhh, const int* __restrict__ seq_len,
    float* __restrict__ hfin) {
  __shared__ float sW[DD * 192];
  __shared__ float hT[DD * GHSTR];
  const int tid = threadIdx.x;
  for (int i = tid; i < DD * 192; i += 256) sW[i] = Whh[i];
  const int ct = tid & 15, rt = tid >> 4;
  const int d0 = ct * 4, r0 = rt * 2;
  const int row0 = blockIdx.x * 32;
  float bR[4], bZ[4], bN[4];
#pragma unroll
  for (int dd = 0; dd < 4; ++dd) {
    bR[dd] = bhh[d0 + dd];
    bZ[dd] = bhh[64 + d0 + dd];
    bN[dd] = bhh[128 + d0 + dd];
  }
  const int sl0 = seq_len[row0 + r0], sl1 = seq_len[row0 + r0 + 1];
  float h0[4] = {0.f, 0.f, 0.f, 0.f}, h1[4] = {0.f, 0.f, 0.f, 0.f};
  const us_t* ga = gi + (long)(row0 + r0) * TT * 192;
  const us_t* gb = gi + (long)(row0 + r0 + 1) * TT * 192;
  ushort4 pa0 = *(const ushort4*)(ga + d0);
  ushort4 pa1 = *(const ushort4*)(ga + 64 + d0);
  ushort4 pa2 = *(const ushort4*)(ga + 128 + d0);
  ushort4 pb0 = *(const ushort4*)(gb + d0);
  ushort4 pb1 = *(const ushort4*)(gb + 64 + d0);
  ushort4 pb2 = *(const ushort4*)(gb + 128 + d0);
  __syncthreads();

  for (int t = 0; t < TT; ++t) {
#pragma unroll
    for (int dd = 0; dd < 4; ++dd) {
      hT[(d0 + dd) * GHSTR + r0] = h0[dd];
      hT[(d0 + dd) * GHSTR + r0 + 1] = h1[dd];
    }
    ushort4 na0, na1, na2, nb0, nb1, nb2;
    if (t + 1 < TT) {
      const us_t* a = ga + (long)(t + 1) * 192;
      const us_t* b = gb + (long)(t + 1) * 192;
      na0 = *(const ushort4*)(a + d0);
      na1 = *(const ushort4*)(a + 64 + d0);
      na2 = *(const ushort4*)(a + 128 + d0);
      nb0 = *(const ushort4*)(b + d0);
      nb1 = *(const ushort4*)(b + 64 + d0);
      nb2 = *(const ushort4*)(b + 128 + d0);
    }
    float aR0[4], aZ0[4], aN0[4], aH0[4];
    float aR1[4], aZ1[4], aN1[4], aH1[4];
    aR0[0] = bR[0] + bf2f(pa0.x); aR0[1] = bR[1] + bf2f(pa0.y);
    aR0[2] = bR[2] + bf2f(pa0.z); aR0[3] = bR[3] + bf2f(pa0.w);
    aZ0[0] = bZ[0] + bf2f(pa1.x); aZ0[1] = bZ[1] + bf2f(pa1.y);
    aZ0[2] = bZ[2] + bf2f(pa1.z); aZ0[3] = bZ[3] + bf2f(pa1.w);
    aN0[0] = bf2f(pa2.x); aN0[1] = bf2f(pa2.y);
    aN0[2] = bf2f(pa2.z); aN0[3] = bf2f(pa2.w);
    aR1[0] = bR[0] + bf2f(pb0.x); aR1[1] = bR[1] + bf2f(pb0.y);
    aR1[2] = bR[2] + bf2f(pb0.z); aR1[3] = bR[3] + bf2f(pb0.w);
    aZ1[0] = bZ[0] + bf2f(pb1.x); aZ1[1] = bZ[1] + bf2f(pb1.y);
    aZ1[2] = bZ[2] + bf2f(pb1.z); aZ1[3] = bZ[3] + bf2f(pb1.w);
    aN1[0] = bf2f(pb2.x); aN1[1] = bf2f(pb2.y);
    aN1[2] = bf2f(pb2.z); aN1[3] = bf2f(pb2.w);
#pragma unroll
    for (int dd = 0; dd < 4; ++dd) {
      aH0[dd] = bN[dd];
      aH1[dd] = bN[dd];
    }
    __syncthreads();
#pragma unroll 8
    for (int k = 0; k < DD; ++k) {
      float2 hh = *(const float2*)&hT[k * GHSTR + r0];
      float4 wr4 = *(const float4*)&sW[k * 192 + d0];
      float4 wz4 = *(const float4*)&sW[k * 192 + 64 + d0];
      float4 wn4 = *(const float4*)&sW[k * 192 + 128 + d0];
      fma4(aR0, hh.x, wr4);
      fma4(aR1, hh.y, wr4);
      fma4(aZ0, hh.x, wz4);
      fma4(aZ1, hh.y, wz4);
      fma4(aH0, hh.x, wn4);
      fma4(aH1, hh.y, wn4);
    }
    const bool m0 = t < sl0, m1 = t < sl1;
#pragma unroll
    for (int dd = 0; dd < 4; ++dd) {
      float rg = 1.f / (1.f + __expf(-aR0[dd]));
      float zg = 1.f / (1.f + __expf(-aZ0[dd]));
      float ng = tanhf(fmaf(rg, aH0[dd], aN0[dd]));
      float hn = fmaf(zg, h0[dd] - ng, ng);
      h0[dd] = m0 ? hn : h0[dd];
      rg = 1.f / (1.f + __expf(-aR1[dd]));
      zg = 1.f / (1.f + __expf(-aZ1[dd]));
      ng = tanhf(fmaf(rg, aH1[dd], aN1[dd]));
      hn = fmaf(zg, h1[dd] - ng, ng);
      h1[dd] = m1 ? hn : h1[dd];
    }
    pa0 = na0; pa1 = na1; pa2 = na2;
    pb0 = nb0; pb1 = nb1; pb2 = nb2;
    __syncthreads();
  }
#pragma unroll
  for (int dd = 0; dd < 4; ++dd) {
    hfin[(long)(row0 + r0) * DD + d0 + dd] = h0[dd];
    hfin[(long)(row0 + r0 + 1) * DD + d0 + dd] = h1[dd];
  }
}

// ---------------- final scoring ----------------

__global__ __launch_bounds__(256) void final_score(
    const float* __restrict__ u_sel, const float* __restrict__ itf,
    const float* __restrict__ hfin, const float* __restrict__ ln_g,
    const float* __restrict__ ln_b, const int* __restrict__ pos_idx,
    const int* __restrict__ neg_idx, const int* __restrict__ pos_beh,
    float* __restrict__ out) {
  __shared__ float partial[4];
  const int lane = threadIdx.x & 63;
  const int wv = threadIdx.x >> 6;
  const float g = ln_g[lane], bo = ln_b[lane];
  float local = 0.f;
  int wid = blockIdx.x * 4 + wv;
  int nw = gridDim.x * 4;
  for (int r = wid; r < BB; r += nw) {
    float uf = u_sel[(long)r * DD + lane] + hfin[(long)r * DD + lane];
    float mu = wave_sum64(uf) * (1.f / DD);
    float xc = uf - mu;
    float var = wave_sum64(xc * xc) * (1.f / DD);
    float un = xc * rsqrtf(var + LN_EPS_) * g + bo;
    float pv = itf[(long)pos_idx[r] * DD + lane];
    float nv = itf[(long)neg_idx[r] * DD + lane];
    float ps = wave_sum64(un * pv);
    float ns = wave_sum64(un * nv);
    float n1 = wave_sum64(un * un);
    float n2 = wave_sum64(pv * pv);
    float n3 = wave_sum64(nv * nv);
    float d = ps - ns;
    float sp = fmaxf(-d, 0.f) + log1pf(__expf(-fabsf(d)));
    int pb = pos_beh[r];
    pb = pb < 0 ? 0 : (pb > 3 ? 3 : pb);
    float bw = pb == 0 ? 1.0f : (pb == 1 ? 1.25f : (pb == 2 ? 1.6f : 2.1f));
    local += sp * bw + REG_COEF_ * (sqrtf(n1) + sqrtf(n2) + sqrtf(n3));
  }
  if (lane == 0) partial[wv] = local;
  __syncthreads();
  if (threadIdx.x == 0) {
    float s = partial[0] + partial[1] + partial[2] + partial[3];
    atomicAdd(out, s * (1.f / BB));
  }
}

extern "C" void kernel_launch(void* const* d_in, const int* in_sizes, int n_in,
                              void* d_out, int out_size, void* d_ws,
                              size_t ws_size, hipStream_t stream) {
  const float* user_emb = (const float*)d_in[0];
  const float* item_emb = (const float*)d_in[1];
  const float* beh_emb = (const float*)d_in[2];
  const float* t_w1 = (const float*)d_in[3];
  const float* t_b1 = (const float*)d_in[4];
  const float* t_w2 = (const float*)d_in[5];
  const float* t_b2 = (const float*)d_in[6];
  const float* gru_w_ih = (const float*)d_in[7];
  const float* gru_w_hh = (const float*)d_in[8];
  const float* gru_b_ih = (const float*)d_in[9];
  const float* gru_b_hh = (const float*)d_in[10];
  const float* gnn_user_w = (const float*)d_in[11];
  const float* gnn_user_b = (const float*)d_in[12];
  const float* gnn_item_w = (const float*)d_in[13];
  const float* gnn_item_b = (const float*)d_in[14];
  const float* ln_g = (const float*)d_in[15];
  const float* ln_b = (const float*)d_in[16];
  const float* ui_vals = (const float*)d_in[17];
  const float* adj_vals = (const float*)d_in[18];
  const float* seq_delta = (const float*)d_in[19];
  const int* ui_rows = (const int*)d_in[20];
  const int* ui_cols = (const int*)d_in[21];
  const int* adj_rows = (const int*)d_in[22];
  const int* adj_cols = (const int*)d_in[23];
  const int* seq_items = (const int*)d_in[24];
  const int* seq_behaviors = (const int*)d_in[25];
  const int* seq_len = (const int*)d_in[26];
  const int* user_idx = (const int*)d_in[27];
  const int* pos_item_idx = (const int*)d_in[28];
  const int* neg_item_idx = (const int*)d_in[29];
  const int* pos_behavior = (const int*)d_in[30];

  // ---- workspace layout ----
  float* ws = (float*)d_ws;
  float* u_a = ws;                               // U*64
  float* it_a = u_a + (long)U_N * DD;            // I*64
  float* it_b = it_a + (long)I_N * DD;           // I*64
  float* hfin = it_b + (long)I_N * DD;           // B*64
  float* u_sel = hfin + (long)BB * DD;           // B*64
  float* end_f = u_sel + (long)BB * DD;

  int2* pairs_ui_row = (int2*)end_f;             // EUI
  int2* pairs_ui_col = pairs_ui_row + N_EUI;     // EUI
  int2* pairs_adj = pairs_ui_col + N_EUI;        // EII

  us_t* gi = (us_t*)(pairs_adj + N_EII);         // B*T*192
  us_t* user_bf = gi + (long)BB * TT * 192;      // U*64
  us_t* item_bf = user_bf + (long)U_N * DD;      // I*64
  us_t* ua_bf = item_bf + (long)I_N * DD;        // U*64
  us_t* ita_bf = ua_bf + (long)U_N * DD;         // I*64

  int* offs_ui_row = (int*)(ita_bf + (long)I_N * DD);
  int* offs_ui_col = offs_ui_row + (U_N + 1);
  int* offs_adj = offs_ui_col + (I_N + 1);
  int* cur_ui_row = offs_adj + (I_N + 1);
  int* cur_ui_col = cur_ui_row + U_N;
  int* cur_adj = cur_ui_col + I_N;

  hipMemsetAsync(d_out, 0, (size_t)out_size * sizeof(float), stream);
  hipMemsetAsync(cur_ui_row, 0, (size_t)(U_N + I_N + I_N) * sizeof(int),
                 stream);

  // ---- bf16 copies of layer-0 gather sources ----
  to_bf16<<<1024, 256, 0, stream>>>(user_emb, user_bf, (long)U_N * DD / 4);
  to_bf16<<<1024, 256, 0, stream>>>(item_emb, item_bf, (long)I_N * DD / 4);

  // ---- CSR build (merged) ----
  hist3<<<2560, 256, 0, stream>>>(ui_rows, ui_cols, adj_rows, cur_ui_row,
                                  cur_ui_col, cur_adj);
  scan3<<<3, 1024, 0, stream>>>(cur_ui_row, offs_ui_row, cur_ui_col,
                                offs_ui_col, cur_adj, offs_adj);
  fill3<<<2560, 256, 0, stream>>>(ui_rows, ui_cols, ui_vals, cur_ui_row,
                                  pairs_ui_row, ui_cols, ui_rows, ui_vals,
                                  cur_ui_col, pairs_ui_col, adj_rows, adj_cols,
                                  adj_vals, cur_adj, pairs_adj);

  // ---- GNN layer 0 (dual-write f32 + bf16) ----
  gnn_user_layer<<<2048, 256, 0, stream>>>(user_emb, item_bf, offs_ui_row,
                                           pairs_ui_row, gnn_user_w,
                                           gnn_user_b, u_a, ua_bf);
  gnn_item_layer<<<2048, 256, 0, stream>>>(item_emb, item_bf, user_bf,
                                           offs_adj, pairs_adj, offs_ui_col,
                                           pairs_ui_col, gnn_item_w,
                                           gnn_item_b, it_a, ita_bf);
  // ---- GNN layer 1 (all items; users only where needed) ----
  gnn_item_layer<<<2048, 256, 0, stream>>>(it_a, ita_bf, ua_bf, offs_adj,
                                           pairs_adj, offs_ui_col,
                                           pairs_ui_col, gnn_item_w + DD * DD,
                                           gnn_item_b + DD, it_b, nullptr);
  gnn_user_sel<<<512, 256, 0, stream>>>(u_a, ita_bf, user_idx, offs_ui_row,
                                        pairs_ui_row, gnn_user_w + DD * DD,
                                        gnn_user_b + DD, u_sel);

  // ---- sequence encoding + gi via MFMA ----
  seq_mfma<<<480, 256, 0, stream>>>(it_b, beh_emb, t_w1, t_b1, t_w2, t_b2,
                                    ln_g, ln_b, gru_w_ih, gru_b_ih, seq_delta,
                                    seq_items, seq_behaviors, gi);

  // ---- GRU scan (hh-half only) ----
  gru_scan4<<<BB / 32, 256, 0, stream>>>(gi, gru_w_hh, gru_b_hh, seq_len,
                                         hfin);

  // ---- final scoring ----
  final_score<<<256, 256, 0, stream>>>(u_sel, it_b, hfin, ln_g, ln_b,
                                       pos_item_idx, neg_item_idx,
                                       pos_behavior, (float*)d_out);
}